// Round 3
// baseline (581.590 us; speedup 1.0000x reference)
//
#include <hip/hip_runtime.h>
#include <hip/hip_bf16.h>
#include <math.h>

// Shapes
#define BB  512
#define SS  23
#define DD  768
#define EE  8
#define NHH 8
#define RR  256
#define HDD 32
#define LL  50
#define HH2 384            // D/2
#define TT  (BB*SS)        // 11776
#define LN_EPS 1e-5f
#define MAXWORK 1536
#define NCTX 4352          // ctxF(2048) | ctxG(2048) | rtrC(256)
#define NACAP 12288        // cand rows capacity (>= 2*#missing; ~11776 expected)

typedef short v8s __attribute__((ext_vector_type(8)));
typedef float v4f __attribute__((ext_vector_type(4)));

__device__ __forceinline__ float gelu(float v){
  return 0.5f*v*(1.f + erff(v*0.70710678118654752f));
}
__device__ __forceinline__ unsigned short f2b(float v){
  __hip_bfloat16 h = __float2bfloat16(v);
  return *reinterpret_cast<unsigned short*>(&h);
}

__device__ __forceinline__ float block_sum(float v, float* red, int nw){
  #pragma unroll
  for (int o = 32; o > 0; o >>= 1) v += __shfl_down(v, o, 64);
  int wid = threadIdx.x >> 6;
  __syncthreads();
  if ((threadIdx.x & 63) == 0) red[wid] = v;
  __syncthreads();
  float s = 0.f;
  for (int i = 0; i < nw; ++i) s += red[i];
  return s;
}

// ---------------- K1: masked-mean context [B,D] (+bf16 copy) ----------------
__global__ void k_context(const float* __restrict__ emb, const int* __restrict__ existing,
                          float* __restrict__ ctx, unsigned short* __restrict__ ctxbf){
  int b = blockIdx.x, tid = threadIdx.x;
  float acc0=0.f, acc1=0.f, acc2=0.f;
  int cnt = 0;
  for (int s = 0; s < SS; ++s){
    if (existing[b*SS + s]){
      ++cnt;
      const float* row = emb + ((size_t)(b*SS + s))*DD;
      acc0 += row[tid]; acc1 += row[tid+256]; acc2 += row[tid+512];
    }
  }
  float inv = 1.0f / ((float)cnt + 1e-8f);
  float v0 = acc0*inv, v1 = acc1*inv, v2 = acc2*inv;
  ctx[(size_t)b*DD + tid      ] = v0;
  ctx[(size_t)b*DD + tid + 256] = v1;
  ctx[(size_t)b*DD + tid + 512] = v2;
  ctxbf[(size_t)b*DD + tid      ] = f2b(v0);
  ctxbf[(size_t)b*DD + tid + 256] = f2b(v1);
  ctxbf[(size_t)b*DD + tid + 512] = f2b(v2);
}

// ---------------- K-mtpad: mt [23][768] -> mtbf [64][768] bf16 (zero pad) ----------------
__global__ void k_mtpad(const float* __restrict__ mt, unsigned short* __restrict__ mtbf){
  int row = blockIdx.x, tid = threadIdx.x;
  #pragma unroll
  for (int j = 0; j < 3; ++j){
    int d = tid + j*256;
    float v = (row < SS) ? mt[(size_t)row*DD + d] : 0.f;
    mtbf[(size_t)row*DD + d] = f2b(v);
  }
}

// ---------------- K-pack: transpose-cast all GEMM weights to bf16 [N][K] ----------------
// ranges: red_w1 288 | qkv 192 | out_w 64 | fus1 1536 | gate1 1536 | fus_w2 1536 | rtr-hi 192
//         | dpe_w0 1536 | dpe_w1 512 | dpe_w2 512 | dpe_wo 1536 | fus_w1p 1536 | gate_w1p 1536
//         | rtr-lo 192 | red_w2 96  => total 12800
__global__ __launch_bounds__(256) void k_pack(
    const float* __restrict__ red_w1, const float* __restrict__ qkv_w,
    const float* __restrict__ out_w,  const float* __restrict__ fus_w1c,
    const float* __restrict__ gate_w1c, const float* __restrict__ fus_w2,
    const float* __restrict__ rtr_w1,
    const float* __restrict__ dpe_w0, const float* __restrict__ dpe_w1,
    const float* __restrict__ dpe_w2, const float* __restrict__ dpe_wo,
    const float* __restrict__ fus_w1p, const float* __restrict__ gate_w1p,
    const float* __restrict__ red_w2,
    unsigned short* __restrict__ Wr1t, unsigned short* __restrict__ Wqt,
    unsigned short* __restrict__ Wot,  unsigned short* __restrict__ Wct,
    unsigned short* __restrict__ Wf2t,
    unsigned short* __restrict__ W0t,  unsigned short* __restrict__ W1t,
    unsigned short* __restrict__ W2t,  unsigned short* __restrict__ Wot2,
    unsigned short* __restrict__ Wpgt, unsigned short* __restrict__ Wr1rt,
    unsigned short* __restrict__ Wr2t){
  int t = blockIdx.x, tid = threadIdx.x;
  const float* src; unsigned short* dst;
  int Nsrc, stride, tk, tn;
  if (t < 288){ src = red_w1; dst = Wr1t; Nsrc = 384; stride = 768; tk = t % 24; tn = t / 24; }
  else if (t < 480){
    int u = t - 288, m = u >> 6, v2 = u & 63;
    src = qkv_w + (size_t)m*256*256; dst = Wqt + (size_t)m*256*256;
    Nsrc = 256; stride = 256; tk = v2 & 7; tn = v2 >> 3;
  } else if (t < 544){
    int v2 = t - 480;
    src = out_w; dst = Wot; Nsrc = 256; stride = 256; tk = v2 & 7; tn = v2 >> 3;
  } else if (t < 2080){
    int u = t - 544, e = u / 192, v2 = u % 192;
    src = fus_w1c + (size_t)e*DD*RR; dst = Wct + (size_t)(e*256)*768;
    Nsrc = 256; stride = 768; tk = v2 % 24; tn = v2 / 24;
  } else if (t < 3616){
    int u = t - 2080, e = u / 192, v2 = u % 192;
    src = gate_w1c + (size_t)e*DD*RR; dst = Wct + (size_t)(2048 + e*256)*768;
    Nsrc = 256; stride = 768; tk = v2 % 24; tn = v2 / 24;
  } else if (t < 5152){
    // fus_w2 [E][256][768] -> Wf2t [E][768][256]
    int u = t - 3616, e = u / 192, v2 = u % 192;
    src = fus_w2 + (size_t)e*RR*DD; dst = Wf2t + (size_t)e*768*256;
    Nsrc = 768; stride = 256; tk = v2 & 7; tn = v2 >> 3;
  } else if (t < 5344){
    int u = t - 5152;
    src = rtr_w1 + (size_t)768*256; dst = Wct + (size_t)4096*768;
    Nsrc = 256; stride = 768; tk = u % 24; tn = u / 24;
  } else if (t < 6880){
    // dpe_w0 [E][768][256] -> W0t [E][256][768]
    int u = t - 5344, e = u / 192, v2 = u % 192;
    src = dpe_w0 + (size_t)e*DD*RR; dst = W0t + (size_t)e*256*768;
    Nsrc = 256; stride = 768; tk = v2 % 24; tn = v2 / 24;
  } else if (t < 7392){
    int u = t - 6880, e = u / 64, v2 = u % 64;
    src = dpe_w1 + (size_t)e*RR*RR; dst = W1t + (size_t)e*256*256;
    Nsrc = 256; stride = 256; tk = v2 & 7; tn = v2 >> 3;
  } else if (t < 7904){
    int u = t - 7392, e = u / 64, v2 = u % 64;
    src = dpe_w2 + (size_t)e*RR*RR; dst = W2t + (size_t)e*256*256;
    Nsrc = 256; stride = 256; tk = v2 & 7; tn = v2 >> 3;
  } else if (t < 9440){
    // dpe_wo [E][256][768] -> Wot2 [E][768][256]
    int u = t - 7904, e = u / 192, v2 = u % 192;
    src = dpe_wo + (size_t)e*RR*DD; dst = Wot2 + (size_t)e*768*256;
    Nsrc = 768; stride = 256; tk = v2 & 7; tn = v2 >> 3;
  } else if (t < 10976){
    // fus_w1p [E][768][256] -> Wpgt [E][0:256][768]
    int u = t - 9440, e = u / 192, v2 = u % 192;
    src = fus_w1p + (size_t)e*DD*RR; dst = Wpgt + (size_t)e*512*768;
    Nsrc = 256; stride = 768; tk = v2 % 24; tn = v2 / 24;
  } else if (t < 12512){
    // gate_w1p -> Wpgt [E][256:512][768]
    int u = t - 10976, e = u / 192, v2 = u % 192;
    src = gate_w1p + (size_t)e*DD*RR; dst = Wpgt + (size_t)e*512*768 + (size_t)256*768;
    Nsrc = 256; stride = 768; tk = v2 % 24; tn = v2 / 24;
  } else if (t < 12704){
    // rtr_w1 rows 0..767 -> Wr1rt [256][768]
    int u = t - 12512;
    src = rtr_w1; dst = Wr1rt;
    Nsrc = 256; stride = 768; tk = u % 24; tn = u / 24;
  } else {
    // red_w2 [384][256] -> Wr2t [256][384]
    int u = t - 12704;
    src = red_w2; dst = Wr2t;
    Nsrc = 256; stride = 384; tk = u % 12; tn = u / 12;
  }
  __shared__ float lt[32][33];
  int i0 = tid >> 5, j = tid & 31;
  #pragma unroll
  for (int l = 0; l < 4; ++l){
    int i = i0 + l*8;
    lt[i][j] = src[(size_t)(tk*32 + i)*Nsrc + tn*32 + j];
  }
  __syncthreads();
  #pragma unroll
  for (int l = 0; l < 4; ++l){
    int i = i0 + l*8;
    dst[(size_t)(tn*32 + i)*stride + tk*32 + j] = f2b(lt[j][i]);
  }
}

// ---------------- K-gemm: C[M][N] = A[M][K](bf16) @ Bt[N][K](bf16) + bias; epi ----------------
// epi: 0=none, 1=+bias, 2=gelu(+bias) fp32 out, 3=gelu(+bias) -> bf16 out
__global__ __launch_bounds__(256) void k_gemm(
    const unsigned short* __restrict__ A, const unsigned short* __restrict__ Bt,
    const float* __restrict__ bias, float* __restrict__ C,
    int M, int N, int K, int epi){
  int m0 = blockIdx.x * 64, n0 = blockIdx.y * 64;
  int tid = threadIdx.x;
  int w = tid >> 6, lane = tid & 63;
  int fm = lane & 15, q = lane >> 4;
  __shared__ unsigned short As[64*72];
  __shared__ unsigned short Bs[64*72];
  v4f acc[4] = {};
  int sr = tid >> 2, scb = (tid & 3) * 16;
  const unsigned short* Aga = A + (size_t)(m0 + sr)*K + scb;
  const unsigned short* Bga = Bt + (size_t)(n0 + sr)*K + scb;
  unsigned short* Asd = As + sr*72 + scb;
  unsigned short* Bsd = Bs + sr*72 + scb;
  for (int k0 = 0; k0 < K; k0 += 64){
    uint4 a0 = *(const uint4*)(Aga + k0);
    uint4 a1 = *(const uint4*)(Aga + k0 + 8);
    uint4 b0 = *(const uint4*)(Bga + k0);
    uint4 b1 = *(const uint4*)(Bga + k0 + 8);
    __syncthreads();
    *(uint4*)Asd = a0; *(uint4*)(Asd + 8) = a1;
    *(uint4*)Bsd = b0; *(uint4*)(Bsd + 8) = b1;
    __syncthreads();
    const unsigned short* ap = As + (w*16 + fm)*72 + q*8;
    const unsigned short* bp = Bs + fm*72 + q*8;
    #pragma unroll
    for (int kk = 0; kk < 2; ++kk){
      v8s af = *(const v8s*)(ap + kk*32);
      #pragma unroll
      for (int j = 0; j < 4; ++j){
        v8s bf = *(const v8s*)(bp + j*16*72 + kk*32);
        acc[j] = __builtin_amdgcn_mfma_f32_16x16x32_bf16(af, bf, acc[j], 0, 0, 0);
      }
    }
  }
  #pragma unroll
  for (int j = 0; j < 4; ++j){
    int n = n0 + j*16 + fm;
    float bv = bias ? bias[n] : 0.f;
    if (epi == 3){
      unsigned short* Cp = (unsigned short*)C + (size_t)(m0 + w*16 + q*4)*N + n;
      #pragma unroll
      for (int r = 0; r < 4; ++r)
        Cp[(size_t)r*N] = f2b(gelu(acc[j][r] + bv));
    } else {
      float* Cp = C + (size_t)(m0 + w*16 + q*4)*N + n;
      #pragma unroll
      for (int r = 0; r < 4; ++r){
        float v = acc[j][r] + bv;
        if (epi == 2) v = gelu(v);
        Cp[(size_t)r*N] = v;
      }
    }
  }
}

// ---------------- K-gemmb: batched 64x64-tile GEMM (grid.z = batch) ----------------
// epi 0: relu -> bf16 out ; epi 1: fp32 out (+bias if bias)
__global__ __launch_bounds__(256) void k_gemmb(
    const unsigned short* __restrict__ A, size_t sA,
    const unsigned short* __restrict__ Bt, size_t sB,
    const float* __restrict__ bias, int sbias,
    void* __restrict__ C, size_t sC,
    int M, int N, int K, int epi){
  int e = blockIdx.z;
  const unsigned short* Ae = A + (size_t)e*sA;
  const unsigned short* Be = Bt + (size_t)e*sB;
  const float* biase = bias ? (bias + (size_t)e*sbias) : (const float*)nullptr;
  int m0 = blockIdx.x * 64, n0 = blockIdx.y * 64;
  int tid = threadIdx.x;
  int w = tid >> 6, lane = tid & 63;
  int fm = lane & 15, q = lane >> 4;
  __shared__ unsigned short As[64*72];
  __shared__ unsigned short Bs[64*72];
  v4f acc[4] = {};
  int sr = tid >> 2, scb = (tid & 3) * 16;
  const unsigned short* Aga = Ae + (size_t)(m0 + sr)*K + scb;
  const unsigned short* Bga = Be + (size_t)(n0 + sr)*K + scb;
  unsigned short* Asd = As + sr*72 + scb;
  unsigned short* Bsd = Bs + sr*72 + scb;
  for (int k0 = 0; k0 < K; k0 += 64){
    uint4 a0 = *(const uint4*)(Aga + k0);
    uint4 a1 = *(const uint4*)(Aga + k0 + 8);
    uint4 b0 = *(const uint4*)(Bga + k0);
    uint4 b1 = *(const uint4*)(Bga + k0 + 8);
    __syncthreads();
    *(uint4*)Asd = a0; *(uint4*)(Asd + 8) = a1;
    *(uint4*)Bsd = b0; *(uint4*)(Bsd + 8) = b1;
    __syncthreads();
    const unsigned short* ap = As + (w*16 + fm)*72 + q*8;
    const unsigned short* bp = Bs + fm*72 + q*8;
    #pragma unroll
    for (int kk = 0; kk < 2; ++kk){
      v8s af = *(const v8s*)(ap + kk*32);
      #pragma unroll
      for (int j = 0; j < 4; ++j){
        v8s bf = *(const v8s*)(bp + j*16*72 + kk*32);
        acc[j] = __builtin_amdgcn_mfma_f32_16x16x32_bf16(af, bf, acc[j], 0, 0, 0);
      }
    }
  }
  #pragma unroll
  for (int j = 0; j < 4; ++j){
    int n = n0 + j*16 + fm;
    float bv = biase ? biase[n] : 0.f;
    #pragma unroll
    for (int r = 0; r < 4; ++r){
      float v = acc[j][r] + bv;
      int m = m0 + w*16 + q*4 + r;
      if (epi == 0){
        unsigned short* Cb = (unsigned short*)C + (size_t)e*sC;
        Cb[(size_t)m*N + n] = f2b(fmaxf(v, 0.f));
      } else {
        float* Cf = (float*)C + (size_t)e*sC;
        Cf[(size_t)m*N + n] = v;
      }
    }
  }
}

// ---------------- K-posLN: LN(dpeout + mt) -> posbf [E][64][768] bf16 (pad rows = 0) ----
__global__ void k_posLN(const float* __restrict__ dpeout, const float* __restrict__ mt,
                        const float* __restrict__ lng, const float* __restrict__ lnb,
                        unsigned short* __restrict__ posbf){
  int e = blockIdx.x >> 6, s = blockIdx.x & 63, tid = threadIdx.x;
  size_t ro = (size_t)(e*64 + s)*DD;
  if (s >= SS){
    for (int j = tid; j < DD; j += 256) posbf[ro + j] = 0;
    return;
  }
  __shared__ float red[8];
  float o[3];
  #pragma unroll
  for (int j = 0; j < 3; ++j){
    int d = tid + j*256;
    o[j] = dpeout[ro + d] + mt[(size_t)s*DD + d];
  }
  float mean = block_sum(o[0]+o[1]+o[2], red, 4) * (1.f/DD);
  float dv = 0.f;
  #pragma unroll
  for (int j = 0; j < 3; ++j){ float c = o[j]-mean; dv += c*c; }
  float rstd = rsqrtf(block_sum(dv, red, 4) * (1.f/DD) + LN_EPS);
  #pragma unroll
  for (int j = 0; j < 3; ++j){
    int d = tid + j*256;
    posbf[ro + d] = f2b((o[j]-mean)*rstd*lng[e*DD + d] + lnb[e*DD + d]);
  }
}

// ---------------- K4: router, one token per wave -> per-expert buckets ----------------
__global__ __launch_bounds__(256) void k_router(
    const float* __restrict__ emb, const int* __restrict__ existing,
    const float* __restrict__ rtrD, const float* __restrict__ ctxFGR,
    const float* __restrict__ rb1, const float* __restrict__ rw2,
    const float* __restrict__ rb2,
    int* __restrict__ cntE, int* __restrict__ listE,
    int* __restrict__ bp0, int* __restrict__ bp1, float* __restrict__ w01,
    unsigned short* __restrict__ secbf){
  int wv = threadIdx.x >> 6, lane = threadIdx.x & 63;
  int t = blockIdx.x*4 + wv;
  if (existing[t]){
    const float4* src = (const float4*)(emb + (size_t)t*DD);
    uint2* dst = (uint2*)(secbf + (size_t)t*DD);
    #pragma unroll
    for (int j = 0; j < 3; ++j){
      float4 x = src[lane + j*64];
      uint2 pk;
      pk.x = (unsigned)f2b(x.x) | ((unsigned)f2b(x.y) << 16);
      pk.y = (unsigned)f2b(x.z) | ((unsigned)f2b(x.w) << 16);
      dst[lane + j*64] = pk;
    }
    return;
  }
  int b = t / SS, s = t - b*SS;
  const float* rtrC = ctxFGR + (size_t)b*NCTX + 4096;
  float acc[EE] = {};
  #pragma unroll
  for (int j = 0; j < 4; ++j){
    int idx = lane + j*64;
    float hr = fmaxf(rtrD[s*RR + idx] + rtrC[idx] + rb1[idx], 0.f);
    #pragma unroll
    for (int e = 0; e < EE; ++e) acc[e] += hr * rw2[idx*EE + e];
  }
  #pragma unroll
  for (int e = 0; e < EE; ++e)
    #pragma unroll
    for (int o = 32; o > 0; o >>= 1) acc[e] += __shfl_xor(acc[e], o, 64);
  if (lane == 0){
    float sc[EE];
    float m = -1e30f;
    #pragma unroll
    for (int e = 0; e < EE; ++e){ sc[e] = acc[e] + rb2[e]; m = fmaxf(m, sc[e]); }
    float w[EE]; float Z = 0.f;
    #pragma unroll
    for (int e = 0; e < EE; ++e){ w[e] = expf(sc[e]-m); Z += w[e]; }
    int i0 = 0;
    for (int e = 1; e < EE; ++e) if (w[e] > w[i0]) i0 = e;
    int i1 = -1;
    for (int e = 0; e < EE; ++e) if (e != i0 && (i1 < 0 || w[e] > w[i1])) i1 = e;
    float iz = 1.f/Z;
    int sl0 = atomicAdd(&cntE[i0], 1);
    int sl1 = atomicAdd(&cntE[i1], 1);
    if (sl0 >= TT) sl0 = TT - 1;
    if (sl1 >= TT) sl1 = TT - 1;
    listE[i0*TT + sl0] = t;
    listE[i1*TT + sl1] = t;
    bp0[t] = (i0 << 16) | sl0; w01[2*t]   = w[i0]*iz;
    bp1[t] = (i1 << 16) | sl1; w01[2*t+1] = w[i1]*iz;
  }
}

// ---------------- K4b: expert offsets + (expert,chunk) work list ----------------
__global__ void k_offsE(const int* __restrict__ cntE, int* __restrict__ offE,
                        int* __restrict__ workE, int* __restrict__ wtotE){
  if (threadIdx.x == 0){
    int acc = 0, wb = 0;
    for (int e = 0; e < EE; ++e){
      offE[e] = acc;
      int n = cntE[e]; if (n > TT) n = TT;
      acc += n;
      int nb = (n + 63) >> 6;
      for (int j = 0; j < nb && wb < MAXWORK; ++j) workE[wb++] = (e << 16) | j;
    }
    wtotE[0] = wb;
  }
}

// ---------------- K5a: hf = relu(ctxF+posF+fb1) -> bf16 global; gates ----------------
__global__ __launch_bounds__(256) void k_hfE(
    const float* __restrict__ ctxFGR, const float* __restrict__ posFG,
    const float* __restrict__ fb1,
    const float* __restrict__ gb1, const float* __restrict__ gw2,
    const float* __restrict__ gb2,
    const int* __restrict__ cntE, const int* __restrict__ offE,
    const int* __restrict__ listE,
    const int* __restrict__ workE, const int* __restrict__ wtotE,
    unsigned short* __restrict__ hfg, float* __restrict__ gatesg){
  int wi = blockIdx.x;
  if (wi >= wtotE[0]) return;
  int ent = workE[wi];
  int e = ent >> 16, chunk = ent & 0xffff;
  int n = cntE[e]; if (n > TT) n = TT;
  int nt = n - chunk*64; if (nt > 64) nt = 64;
  int base = offE[e] + chunk*64;
  int tid = threadIdx.x, wv = tid >> 6, lane = tid & 63;
  __shared__ int tb[64], ts[64];
  if (tid < 64){
    int ok = tid < nt;
    int t = listE[e*TT + chunk*64 + (ok ? tid : 0)];
    tb[tid] = t/SS; ts[tid] = t - (t/SS)*SS;
  }
  __syncthreads();
  {
    int row = tid >> 2, cb = (tid & 3) * 64;
    if (row < nt){
      int b = tb[row], s = ts[row];
      const float4* cF = (const float4*)(ctxFGR + (size_t)b*NCTX + e*256 + cb);
      const float4* pF = (const float4*)(posFG + ((size_t)(e*64 + s))*512 + cb);
      const float4* bF = (const float4*)(fb1 + (size_t)e*RR + cb);
      uint2* dst = (uint2*)(hfg + (size_t)(base + row)*256 + cb);
      #pragma unroll
      for (int j = 0; j < 16; ++j){
        float4 a = cF[j], p = pF[j], bb = bF[j];
        uint2 pk;
        pk.x = (unsigned)f2b(fmaxf(a.x+p.x+bb.x, 0.f))
             | ((unsigned)f2b(fmaxf(a.y+p.y+bb.y, 0.f)) << 16);
        pk.y = (unsigned)f2b(fmaxf(a.z+p.z+bb.z, 0.f))
             | ((unsigned)f2b(fmaxf(a.w+p.w+bb.w, 0.f)) << 16);
        dst[j] = pk;
      }
    }
  }
  for (int ii = 0; ii < 16; ++ii){
    int row = wv*16 + ii;
    if (row < nt){
      int b = tb[row], s = ts[row];
      float g = 0.f;
      #pragma unroll
      for (int j = 0; j < 4; ++j){
        int idx = lane + j*64;
        float hg = fmaxf(ctxFGR[(size_t)b*NCTX + 2048 + e*256 + idx]
                         + posFG[((size_t)(e*64 + s))*512 + 256 + idx] + gb1[e*RR + idx], 0.f);
        g += hg * gw2[e*RR + idx];
      }
      #pragma unroll
      for (int o = 32; o > 0; o >>= 1) g += __shfl_xor(g, o, 64);
      if (lane == 0) gatesg[base + row] = 1.f/(1.f + expf(-(g + gb2[e])));
    }
  }
}

// ---------------- K5b: expert GEMM tile (chunk, nc) -> cand (pre-LN mix) ----------------
__global__ __launch_bounds__(256) void k_gemmE(
    const unsigned short* __restrict__ hfg, const unsigned short* __restrict__ Wf2t,
    const float* __restrict__ fb2, const float* __restrict__ ctx,
    const float* __restrict__ gatesg,
    const int* __restrict__ cntE, const int* __restrict__ offE,
    const int* __restrict__ listE,
    const int* __restrict__ workE, const int* __restrict__ wtotE,
    float* __restrict__ cand){
  int wi = blockIdx.x;
  if (wi >= wtotE[0]) return;
  int ent = workE[wi];
  int e = ent >> 16, chunk = ent & 0xffff;
  int n = cntE[e]; if (n > TT) n = TT;
  int nt = n - chunk*64; if (nt > 64) nt = 64;
  int base = offE[e] + chunk*64;
  int nc = blockIdx.y;
  int tid = threadIdx.x, w = tid >> 6, lane = tid & 63;
  int fm = lane & 15, q = lane >> 4;
  __shared__ unsigned short As[64*72];
  __shared__ unsigned short Bs[64*72];
  __shared__ float gl[64];
  __shared__ int tbl[64];
  if (tid < 64){
    int ok = tid < nt;
    int t = listE[e*TT + chunk*64 + (ok ? tid : 0)];
    tbl[tid] = t/SS;
    gl[tid] = gatesg[base + (ok ? tid : 0)];
  }
  v4f acc[4] = {};
  int sr = tid >> 2, scb = (tid & 3) * 16;
  const unsigned short* Aga = hfg + (size_t)(base + sr)*256 + scb;
  const unsigned short* Bga = Wf2t + (size_t)e*768*256 + (size_t)(nc*64 + sr)*256 + scb;
  unsigned short* Asd = As + sr*72 + scb;
  unsigned short* Bsd = Bs + sr*72 + scb;
  for (int k0 = 0; k0 < 256; k0 += 64){
    uint4 a0 = *(const uint4*)(Aga + k0);
    uint4 a1 = *(const uint4*)(Aga + k0 + 8);
    uint4 b0 = *(const uint4*)(Bga + k0);
    uint4 b1 = *(const uint4*)(Bga + k0 + 8);
    __syncthreads();
    *(uint4*)Asd = a0; *(uint4*)(Asd + 8) = a1;
    *(uint4*)Bsd = b0; *(uint4*)(Bsd + 8) = b1;
    __syncthreads();
    const unsigned short* ap = As + (w*16 + fm)*72 + q*8;
    const unsigned short* bp = Bs + fm*72 + q*8;
    #pragma unroll
    for (int kk = 0; kk < 2; ++kk){
      v8s af = *(const v8s*)(ap + kk*32);
      #pragma unroll
      for (int j = 0; j < 4; ++j){
        v8s bf = *(const v8s*)(bp + j*16*72 + kk*32);
        acc[j] = __builtin_amdgcn_mfma_f32_16x16x32_bf16(af, bf, acc[j], 0, 0, 0);
      }
    }
  }
  #pragma unroll
  for (int j = 0; j < 4; ++j){
    int d = nc*64 + j*16 + fm;
    float fb2v = fb2[(size_t)e*DD + d];
    #pragma unroll
    for (int r = 0; r < 4; ++r){
      int row = w*16 + q*4 + r;
      if (row < nt){
        float g = gl[row];
        float cv = ctx[(size_t)tbl[row]*DD + d];
        cand[(size_t)(base + row)*DD + d] = g*(acc[j][r] + fb2v) + (1.f - g)*cv;
      }
    }
  }
}

// ---------------- K6: per-token gather: LN both cand rows, weighted combine -> secbf --
__global__ void k_gather(const int* __restrict__ existing,
                         const int* __restrict__ bp0, const int* __restrict__ bp1,
                         const float* __restrict__ w01, const int* __restrict__ offE,
                         const float* __restrict__ cand,
                         const float* __restrict__ elng, const float* __restrict__ elnb,
                         unsigned short* __restrict__ secbf){
  int wv = threadIdx.x >> 6, lane = threadIdx.x & 63;
  int t = blockIdx.x*4 + wv;
  if (existing[t]) return;
  int b0v = bp0[t], b1v = bp1[t];
  int e0 = b0v >> 16, e1 = b1v >> 16;
  int g0 = offE[e0] + (b0v & 0xffff);
  int g1 = offE[e1] + (b1v & 0xffff);
  if (g0 >= NACAP) g0 = 0;
  if (g1 >= NACAP) g1 = 0;
  float w0 = w01[2*t], w1 = w01[2*t+1];
  float v0[12], v1[12];
  float s0 = 0.f, q0 = 0.f, s1 = 0.f, q1 = 0.f;
  #pragma unroll
  for (int j = 0; j < 12; ++j){
    int d = lane + j*64;
    v0[j] = cand[(size_t)g0*DD + d];
    v1[j] = cand[(size_t)g1*DD + d];
    s0 += v0[j]; q0 += v0[j]*v0[j];
    s1 += v1[j]; q1 += v1[j]*v1[j];
  }
  #pragma unroll
  for (int o = 32; o > 0; o >>= 1){
    s0 += __shfl_xor(s0, o, 64); q0 += __shfl_xor(q0, o, 64);
    s1 += __shfl_xor(s1, o, 64); q1 += __shfl_xor(q1, o, 64);
  }
  float mean0 = s0*(1.f/DD), mean1 = s1*(1.f/DD);
  float rstd0 = rsqrtf(q0*(1.f/DD) - mean0*mean0 + LN_EPS);
  float rstd1 = rsqrtf(q1*(1.f/DD) - mean1*mean1 + LN_EPS);
  #pragma unroll
  for (int j = 0; j < 12; ++j){
    int d = lane + j*64;
    float o0 = (v0[j]-mean0)*rstd0*elng[e0*DD + d] + elnb[e0*DD + d];
    float o1 = (v1[j]-mean1)*rstd1*elng[e1*DD + d] + elnb[e1*DD + d];
    secbf[(size_t)t*DD + d] = f2b(w0*o0 + w1*o1);
  }
}

// ---------------- K7b: row-LN over R=256 -> bf16 (wave per row) ----------------
__global__ void k_lnR(const float* __restrict__ x2f,
                      const float* __restrict__ lng, const float* __restrict__ lnb,
                      unsigned short* __restrict__ xrbf){
  int wv = threadIdx.x >> 6, lane = threadIdx.x & 63;
  int t = blockIdx.x*4 + wv;
  float v[4];
  float s = 0.f, q = 0.f;
  #pragma unroll
  for (int j = 0; j < 4; ++j){
    v[j] = x2f[(size_t)t*RR + lane + j*64];
    s += v[j]; q += v[j]*v[j];
  }
  #pragma unroll
  for (int o = 32; o > 0; o >>= 1){
    s += __shfl_xor(s, o, 64); q += __shfl_xor(q, o, 64);
  }
  float mean = s*(1.f/RR);
  float rstd = rsqrtf(q*(1.f/RR) - mean*mean + LN_EPS);
  #pragma unroll
  for (int j = 0; j < 4; ++j){
    int d = lane + j*64;
    xrbf[(size_t)t*RR + d] = f2b((v[j]-mean)*rstd*lng[d] + lnb[d]);
  }
}

// ---------------- K9: attention per (b,head); reads qcat [T][768]; writes bf16 ----------------
__global__ void k_attn(const float* __restrict__ qcat, unsigned short* __restrict__ attnbf){
  int bh = blockIdx.x, b = bh / NHH, h = bh % NHH, tid = threadIdx.x;
  __shared__ float qs[SS][HDD], ks[SS][HDD], vs[SS][HDD];
  __shared__ float scr[SS][SS+1];
  for (int idx = tid; idx < SS*HDD; idx += 256){
    int s = idx / HDD, d = idx % HDD;
    size_t g = ((size_t)(b*SS + s))*768 + h*HDD + d;
    qs[s][d] = qcat[g]; ks[s][d] = qcat[g + 256]; vs[s][d] = qcat[g + 512];
  }
  __syncthreads();
  const float scale = 0.17677669529663687f;  // 1/sqrt(32)
  for (int idx = tid; idx < SS*SS; idx += 256){
    int qi = idx / SS, ki = idx % SS;
    float a = 0.f;
    #pragma unroll
    for (int d = 0; d < HDD; ++d) a += qs[qi][d]*ks[ki][d];
    scr[qi][ki] = a*scale;
  }
  __syncthreads();
  if (tid < SS){
    float m = -1e30f;
    for (int ki = 0; ki < SS; ++ki) m = fmaxf(m, scr[tid][ki]);
    float Z = 0.f;
    for (int ki = 0; ki < SS; ++ki){ float e2 = expf(scr[tid][ki]-m); scr[tid][ki] = e2; Z += e2; }
    float iz = 1.f/Z;
    for (int ki = 0; ki < SS; ++ki) scr[tid][ki] *= iz;
  }
  __syncthreads();
  for (int idx = tid; idx < SS*HDD; idx += 256){
    int qi = idx / HDD, d = idx % HDD;
    float a = 0.f;
    for (int ki = 0; ki < SS; ++ki) a += scr[qi][ki]*vs[ki][d];
    attnbf[((size_t)(b*SS + qi))*RR + h*HDD + d] = f2b(a);
  }
}

// ---------------- K10: mean over S + predictor -> logits fp32 ----------------
__global__ void k_final(const float* __restrict__ oproj, const float* __restrict__ pw,
                        const float* __restrict__ pb, float* __restrict__ out){
  int b = blockIdx.x, tid = threadIdx.x;
  __shared__ float om[RR];
  float a = 0.f;
  for (int s = 0; s < SS; ++s) a += oproj[((size_t)(b*SS + s))*RR + tid];
  om[tid] = a * (1.f/SS);
  __syncthreads();
  if (tid < LL){
    float acc = pb[tid];
    for (int h = 0; h < RR; ++h) acc += om[h]*pw[h*LL + tid];
    out[b*LL + tid] = acc;
  }
}

extern "C" void kernel_launch(void* const* d_in, const int* in_sizes, int n_in,
                              void* d_out, int out_size, void* d_ws, size_t ws_size,
                              hipStream_t stream){
  (void)in_sizes; (void)n_in; (void)out_size; (void)ws_size;
  const float* emb      = (const float*)d_in[0];
  const int*   existing = (const int*)d_in[1];
  const float* mt       = (const float*)d_in[2];
  const float* dpe_w0   = (const float*)d_in[3];
  const float* dpe_b0   = (const float*)d_in[4];
  const float* dpe_w1   = (const float*)d_in[5];
  const float* dpe_b1   = (const float*)d_in[6];
  const float* dpe_w2   = (const float*)d_in[7];
  const float* dpe_b2   = (const float*)d_in[8];
  const float* dpe_wo   = (const float*)d_in[9];
  const float* dpe_bo   = (const float*)d_in[10];
  const float* dpe_lng  = (const float*)d_in[11];
  const float* dpe_lnb  = (const float*)d_in[12];
  const float* fus_w1c  = (const float*)d_in[13];
  const float* fus_w1p  = (const float*)d_in[14];
  const float* fus_b1   = (const float*)d_in[15];
  const float* fus_w2   = (const float*)d_in[16];
  const float* fus_b2   = (const float*)d_in[17];
  const float* gate_w1c = (const float*)d_in[18];
  const float* gate_w1p = (const float*)d_in[19];
  const float* gate_b1  = (const float*)d_in[20];
  const float* gate_w2  = (const float*)d_in[21];
  const float* gate_b2  = (const float*)d_in[22];
  const float* exp_lng  = (const float*)d_in[23];
  const float* exp_lnb  = (const float*)d_in[24];
  const float* rtr_w1   = (const float*)d_in[25];
  const float* rtr_b1   = (const float*)d_in[26];
  const float* rtr_w2   = (const float*)d_in[27];
  const float* rtr_b2   = (const float*)d_in[28];
  const float* red_w1   = (const float*)d_in[29];
  const float* red_b1   = (const float*)d_in[30];
  const float* red_w2   = (const float*)d_in[31];
  const float* red_b2   = (const float*)d_in[32];
  const float* red_lng  = (const float*)d_in[33];
  const float* red_lnb  = (const float*)d_in[34];
  const float* qkv_w    = (const float*)d_in[35];
  const float* qkv_b    = (const float*)d_in[36];
  const float* out_w    = (const float*)d_in[37];
  const float* out_b    = (const float*)d_in[38];
  const float* pred_w   = (const float*)d_in[39];
  const float* pred_b   = (const float*)d_in[40];
  float* out = (float*)d_out;

  // workspace layout (float units); aliases noted
  float* wsf = (float*)d_ws;
  size_t off = 0;
  float* ctx    = wsf + off; off += (size_t)BB*DD;
  unsigned short* ctxbf = (unsigned short*)(wsf + off); off += (size_t)BB*DD/2;
  float* ctxFGR = wsf + off; off += (size_t)BB*NCTX;
  int*   cntE   = (int*)(wsf + off); off += 64;
  int*   workE  = (int*)(wsf + off); off += MAXWORK;
  int*   wtot   = (int*)(wsf + off); off += 64;     // wtot[0]=total, wtot[8..15]=offE
  int*   offE   = wtot + 8;
  // region A: listE/bp/w01 (dead before k_attn) ; attnbf aliases it afterwards
  float* regA   = wsf + off; off += (size_t)128*TT;
  int*   listE  = (int*)regA;                       // EE*TT ints
  int*   bp0    = (int*)regA + (size_t)EE*TT;       // TT
  int*   bp1    = (int*)regA + (size_t)(EE+1)*TT;   // TT
  float* w01    = regA + (size_t)(EE+2)*TT;         // 2*TT floats
  unsigned short* attnbf = (unsigned short*)regA;   // TT*RR ushort <= region
  // region B: secbf (used through gemm red1) ; oprojf aliases it afterwards
  float* regB   = wsf + off; off += (size_t)TT*DD/2;
  unsigned short* secbf = (unsigned short*)regB;
  float* oprojf = regB;                             // TT*RR floats <= region
  // region C: DPE scratch (early) ; cand ; x1bf/x2f ; qcat (late)
  float* regC   = wsf + off; off += (size_t)NACAP*DD;
  float* dpeout = regC;                                     // 8*64*768 fp32
  unsigned short* posbf = (unsigned short*)(regC + 393216); // 8*64*768 bf16
  unsigned short* h0    = (unsigned short*)(regC + 589824); // 8*64*256 bf16
  unsigned short* h1    = (unsigned short*)(regC + 655360);
  unsigned short* h2    = (unsigned short*)(regC + 720896);
  float* cand   = regC;                             // NACAP*768 floats (after DPE dead)
  unsigned short* x1bf = (unsigned short*)regC;     // TT*HH2 bf16 (after cand dead)
  float* x2f    = regC + 4718592;                   // TT*RR fp32 (disjoint from x1bf)
  float* qcat   = regC;                             // TT*768 floats (after x2f dead)
  // region D: hfg (live k_hfE..k_gemmE) ; xrbf aliases afterwards
  float* regD   = wsf + off; off += (size_t)NACAP*256/2;    // 1572864 floats
  unsigned short* hfg  = (unsigned short*)regD;             // NACAP*256 bf16
  unsigned short* xrbf = (unsigned short*)regD;             // TT*RR bf16 <= region
  unsigned short* Wr1t = (unsigned short*)(wsf + off); off += (size_t)768*384/2;
  unsigned short* Wqt  = (unsigned short*)(wsf + off); off += (size_t)768*256/2;
  unsigned short* Wot  = (unsigned short*)(wsf + off); off += (size_t)256*256/2;
  unsigned short* Wct  = (unsigned short*)(wsf + off); off += (size_t)NCTX*768/2;
  unsigned short* Wf2t = (unsigned short*)(wsf + off); off += (size_t)EE*768*256/2;
  unsigned short* mtbf = (unsigned short*)(wsf + off); off += (size_t)64*768/2;
  unsigned short* W0t  = (unsigned short*)(wsf + off); off += (size_t)EE*256*768/2;
  unsigned short* W1t  = (unsigned short*)(wsf + off); off += (size_t)EE*256*256/2;
  unsigned short* W2t  = (unsigned short*)(wsf + off); off += (size_t)EE*256*256/2;
  unsigned short* Wot2 = (unsigned short*)(wsf + off); off += (size_t)EE*768*256/2;
  unsigned short* Wpgt = (unsigned short*)(wsf + off); off += (size_t)EE*512*768/2;
  unsigned short* Wr1rt= (unsigned short*)(wsf + off); off += (size_t)256*768/2;
  unsigned short* Wr2t = (unsigned short*)(wsf + off); off += (size_t)256*384/2;
  float* posFG  = wsf + off; off += (size_t)EE*64*512;
  float* rtrDp  = wsf + off; off += (size_t)64*256;
  float* gatesg = wsf + off; off += (size_t)NACAP;

  k_context<<<BB, 256, 0, stream>>>(emb, existing, ctx, ctxbf);
  k_mtpad  <<<64, 256, 0, stream>>>(mt, mtbf);
  k_pack   <<<12800, 256, 0, stream>>>(red_w1, qkv_w, out_w, fus_w1c, gate_w1c, fus_w2,
                                       rtr_w1, dpe_w0, dpe_w1, dpe_w2, dpe_wo,
                                       fus_w1p, gate_w1p, red_w2,
                                       Wr1t, Wqt, Wot, Wct, Wf2t,
                                       W0t, W1t, W2t, Wot2, Wpgt, Wr1rt, Wr2t);
  // DPE chain as batched bf16 GEMMs (M=64 padded from 23 rows)
  k_gemmb<<<dim3(1,4,8),  256, 0, stream>>>(mtbf, 0, W0t, (size_t)256*768,
                                            dpe_b0, 256, h0, (size_t)64*256,
                                            64, 256, 768, 0);
  k_gemmb<<<dim3(1,4,8),  256, 0, stream>>>(h0, (size_t)64*256, W1t, (size_t)256*256,
                                            dpe_b1, 256, h1, (size_t)64*256,
                                            64, 256, 256, 0);
  k_gemmb<<<dim3(1,4,8),  256, 0, stream>>>(h1, (size_t)64*256, W2t, (size_t)256*256,
                                            dpe_b2, 256, h2, (size_t)64*256,
                                            64, 256, 256, 0);
  k_gemmb<<<dim3(1,12,8), 256, 0, stream>>>(h2, (size_t)64*256, Wot2, (size_t)768*256,
                                            dpe_bo, 768, dpeout, (size_t)64*768,
                                            64, 768, 256, 1);
  k_posLN<<<512, 256, 0, stream>>>(dpeout, mt, dpe_lng, dpe_lnb, posbf);
  k_gemmb<<<dim3(1,8,8),  256, 0, stream>>>(posbf, (size_t)64*768, Wpgt, (size_t)512*768,
                                            (const float*)nullptr, 0, posFG, (size_t)64*512,
                                            64, 512, 768, 1);
  k_gemmb<<<dim3(1,4,1),  256, 0, stream>>>(mtbf, 0, Wr1rt, 0,
                                            (const float*)nullptr, 0, rtrDp, 0,
                                            64, 256, 768, 1);
  {
    dim3 g(BB/64, NCTX/64);   // (8, 68)
    k_gemm <<<g, 256, 0, stream>>>(ctxbf, Wct, (const float*)nullptr, ctxFGR,
                                   BB, NCTX, DD, 0);
  }
  hipMemsetAsync(cntE, 0, 64*sizeof(int), stream);
  k_router <<<TT/4, 256, 0, stream>>>(emb, existing, rtrDp, ctxFGR, rtr_b1, rtr_w2, rtr_b2,
                                      cntE, listE, bp0, bp1, w01, secbf);
  k_offsE  <<<1, 64, 0, stream>>>(cntE, offE, workE, wtot);
  k_hfE    <<<384, 256, 0, stream>>>(ctxFGR, posFG, fus_b1,
                                     gate_b1, gate_w2, gate_b2,
                                     cntE, offE, listE, workE, wtot, hfg, gatesg);
  k_gemmE  <<<dim3(384,12), 256, 0, stream>>>(hfg, Wf2t, fus_b2, ctx, gatesg,
                                              cntE, offE, listE, workE, wtot, cand);
  k_gather <<<TT/4, 256, 0, stream>>>(existing, bp0, bp1, w01, offE, cand,
                                      exp_lng, exp_lnb, secbf);
  {
    dim3 g(TT/64, HH2/64);    // (184, 6)
    k_gemm <<<g, 256, 0, stream>>>(secbf, Wr1t, red_b1, (float*)x1bf, TT, HH2, DD, 3);
  }
  {
    dim3 g(TT/64, RR/64);     // (184, 4)
    k_gemm <<<g, 256, 0, stream>>>(x1bf, Wr2t, red_b2, x2f, TT, RR, HH2, 2);
  }
  k_lnR    <<<TT/4, 256, 0, stream>>>(x2f, red_lng, red_lnb, xrbf);
  {
    dim3 g(TT/64, 768/64);    // (184, 12)
    k_gemm <<<g, 256, 0, stream>>>(xrbf, Wqt, qkv_b, qcat, TT, 768, RR, 1);
  }
  k_attn   <<<BB*NHH, 256, 0, stream>>>(qcat, attnbf);
  {
    dim3 g(TT/64, RR/64);     // (184, 4)
    k_gemm <<<g, 256, 0, stream>>>(attnbf, Wot, out_b, oprojf, TT, RR, RR, 1);
  }
  k_final  <<<BB, 256, 0, stream>>>(oprojf, pred_w, pred_b, out);
}

// Round 4
// 464.635 us; speedup vs baseline: 1.2517x; 1.2517x over previous
//
#include <hip/hip_runtime.h>
#include <hip/hip_bf16.h>
#include <math.h>

// Shapes
#define BB  512
#define SS  23
#define DD  768
#define EE  8
#define NHH 8
#define RR  256
#define HDD 32
#define LL  50
#define HH2 384            // D/2
#define TT  (BB*SS)        // 11776
#define LN_EPS 1e-5f
#define MAXWORK 1536
#define NCTX 4352          // ctxF(2048) | ctxG(2048) | rtrC(256)
#define NACAP 12288        // cand rows capacity (>= 2*#missing; ~11776 expected)
#define CPAD 64            // counter padding (ints) -> one counter per 256B

typedef short v8s __attribute__((ext_vector_type(8)));
typedef float v4f __attribute__((ext_vector_type(4)));

__device__ __forceinline__ float gelu(float v){
  return 0.5f*v*(1.f + erff(v*0.70710678118654752f));
}
__device__ __forceinline__ unsigned short f2b(float v){
  __hip_bfloat16 h = __float2bfloat16(v);
  return *reinterpret_cast<unsigned short*>(&h);
}

__device__ __forceinline__ float block_sum(float v, float* red, int nw){
  #pragma unroll
  for (int o = 32; o > 0; o >>= 1) v += __shfl_down(v, o, 64);
  int wid = threadIdx.x >> 6;
  __syncthreads();
  if ((threadIdx.x & 63) == 0) red[wid] = v;
  __syncthreads();
  float s = 0.f;
  for (int i = 0; i < nw; ++i) s += red[i];
  return s;
}

// ---------------- K1: masked-mean context [B,D] (+bf16 copy) ----------------
__global__ void k_context(const float* __restrict__ emb, const int* __restrict__ existing,
                          float* __restrict__ ctx, unsigned short* __restrict__ ctxbf){
  int b = blockIdx.x, tid = threadIdx.x;
  float acc0=0.f, acc1=0.f, acc2=0.f;
  int cnt = 0;
  for (int s = 0; s < SS; ++s){
    if (existing[b*SS + s]){
      ++cnt;
      const float* row = emb + ((size_t)(b*SS + s))*DD;
      acc0 += row[tid]; acc1 += row[tid+256]; acc2 += row[tid+512];
    }
  }
  float inv = 1.0f / ((float)cnt + 1e-8f);
  float v0 = acc0*inv, v1 = acc1*inv, v2 = acc2*inv;
  ctx[(size_t)b*DD + tid      ] = v0;
  ctx[(size_t)b*DD + tid + 256] = v1;
  ctx[(size_t)b*DD + tid + 512] = v2;
  ctxbf[(size_t)b*DD + tid      ] = f2b(v0);
  ctxbf[(size_t)b*DD + tid + 256] = f2b(v1);
  ctxbf[(size_t)b*DD + tid + 512] = f2b(v2);
}

// ---------------- K-mtpad: mt [23][768] -> mtbf [64][768] bf16 (zero pad) ----------------
__global__ void k_mtpad(const float* __restrict__ mt, unsigned short* __restrict__ mtbf){
  int row = blockIdx.x, tid = threadIdx.x;
  #pragma unroll
  for (int j = 0; j < 3; ++j){
    int d = tid + j*256;
    float v = (row < SS) ? mt[(size_t)row*DD + d] : 0.f;
    mtbf[(size_t)row*DD + d] = f2b(v);
  }
}

// ---------------- K-pack: transpose-cast all GEMM weights to bf16 [N][K] ----------------
// ranges: red_w1 288 | qkv 192 | out_w 64 | fus1 1536 | gate1 1536 | fus_w2 1536 | rtr-hi 192
//         | dpe_w0 1536 | dpe_w1 512 | dpe_w2 512 | dpe_wo 1536 | fus_w1p 1536 | gate_w1p 1536
//         | rtr-lo 192 | red_w2 96  => total 12800
__global__ __launch_bounds__(256) void k_pack(
    const float* __restrict__ red_w1, const float* __restrict__ qkv_w,
    const float* __restrict__ out_w,  const float* __restrict__ fus_w1c,
    const float* __restrict__ gate_w1c, const float* __restrict__ fus_w2,
    const float* __restrict__ rtr_w1,
    const float* __restrict__ dpe_w0, const float* __restrict__ dpe_w1,
    const float* __restrict__ dpe_w2, const float* __restrict__ dpe_wo,
    const float* __restrict__ fus_w1p, const float* __restrict__ gate_w1p,
    const float* __restrict__ red_w2,
    unsigned short* __restrict__ Wr1t, unsigned short* __restrict__ Wqt,
    unsigned short* __restrict__ Wot,  unsigned short* __restrict__ Wct,
    unsigned short* __restrict__ Wf2t,
    unsigned short* __restrict__ W0t,  unsigned short* __restrict__ W1t,
    unsigned short* __restrict__ W2t,  unsigned short* __restrict__ Wot2,
    unsigned short* __restrict__ Wpgt, unsigned short* __restrict__ Wr1rt,
    unsigned short* __restrict__ Wr2t){
  int t = blockIdx.x, tid = threadIdx.x;
  const float* src; unsigned short* dst;
  int Nsrc, stride, tk, tn;
  if (t < 288){ src = red_w1; dst = Wr1t; Nsrc = 384; stride = 768; tk = t % 24; tn = t / 24; }
  else if (t < 480){
    int u = t - 288, m = u >> 6, v2 = u & 63;
    src = qkv_w + (size_t)m*256*256; dst = Wqt + (size_t)m*256*256;
    Nsrc = 256; stride = 256; tk = v2 & 7; tn = v2 >> 3;
  } else if (t < 544){
    int v2 = t - 480;
    src = out_w; dst = Wot; Nsrc = 256; stride = 256; tk = v2 & 7; tn = v2 >> 3;
  } else if (t < 2080){
    int u = t - 544, e = u / 192, v2 = u % 192;
    src = fus_w1c + (size_t)e*DD*RR; dst = Wct + (size_t)(e*256)*768;
    Nsrc = 256; stride = 768; tk = v2 % 24; tn = v2 / 24;
  } else if (t < 3616){
    int u = t - 2080, e = u / 192, v2 = u % 192;
    src = gate_w1c + (size_t)e*DD*RR; dst = Wct + (size_t)(2048 + e*256)*768;
    Nsrc = 256; stride = 768; tk = v2 % 24; tn = v2 / 24;
  } else if (t < 5152){
    // fus_w2 [E][256][768] -> Wf2t [E][768][256]
    int u = t - 3616, e = u / 192, v2 = u % 192;
    src = fus_w2 + (size_t)e*RR*DD; dst = Wf2t + (size_t)e*768*256;
    Nsrc = 768; stride = 256; tk = v2 & 7; tn = v2 >> 3;
  } else if (t < 5344){
    int u = t - 5152;
    src = rtr_w1 + (size_t)768*256; dst = Wct + (size_t)4096*768;
    Nsrc = 256; stride = 768; tk = u % 24; tn = u / 24;
  } else if (t < 6880){
    // dpe_w0 [E][768][256] -> W0t [E][256][768]
    int u = t - 5344, e = u / 192, v2 = u % 192;
    src = dpe_w0 + (size_t)e*DD*RR; dst = W0t + (size_t)e*256*768;
    Nsrc = 256; stride = 768; tk = v2 % 24; tn = v2 / 24;
  } else if (t < 7392){
    int u = t - 6880, e = u / 64, v2 = u % 64;
    src = dpe_w1 + (size_t)e*RR*RR; dst = W1t + (size_t)e*256*256;
    Nsrc = 256; stride = 256; tk = v2 & 7; tn = v2 >> 3;
  } else if (t < 7904){
    int u = t - 7392, e = u / 64, v2 = u % 64;
    src = dpe_w2 + (size_t)e*RR*RR; dst = W2t + (size_t)e*256*256;
    Nsrc = 256; stride = 256; tk = v2 & 7; tn = v2 >> 3;
  } else if (t < 9440){
    // dpe_wo [E][256][768] -> Wot2 [E][768][256]
    int u = t - 7904, e = u / 192, v2 = u % 192;
    src = dpe_wo + (size_t)e*RR*DD; dst = Wot2 + (size_t)e*768*256;
    Nsrc = 768; stride = 256; tk = v2 & 7; tn = v2 >> 3;
  } else if (t < 10976){
    // fus_w1p [E][768][256] -> Wpgt [E][0:256][768]
    int u = t - 9440, e = u / 192, v2 = u % 192;
    src = fus_w1p + (size_t)e*DD*RR; dst = Wpgt + (size_t)e*512*768;
    Nsrc = 256; stride = 768; tk = v2 % 24; tn = v2 / 24;
  } else if (t < 12512){
    // gate_w1p -> Wpgt [E][256:512][768]
    int u = t - 10976, e = u / 192, v2 = u % 192;
    src = gate_w1p + (size_t)e*DD*RR; dst = Wpgt + (size_t)e*512*768 + (size_t)256*768;
    Nsrc = 256; stride = 768; tk = v2 % 24; tn = v2 / 24;
  } else if (t < 12704){
    // rtr_w1 rows 0..767 -> Wr1rt [256][768]
    int u = t - 12512;
    src = rtr_w1; dst = Wr1rt;
    Nsrc = 256; stride = 768; tk = u % 24; tn = u / 24;
  } else {
    // red_w2 [384][256] -> Wr2t [256][384]
    int u = t - 12704;
    src = red_w2; dst = Wr2t;
    Nsrc = 256; stride = 384; tk = u % 12; tn = u / 12;
  }
  __shared__ float lt[32][33];
  int i0 = tid >> 5, j = tid & 31;
  #pragma unroll
  for (int l = 0; l < 4; ++l){
    int i = i0 + l*8;
    lt[i][j] = src[(size_t)(tk*32 + i)*Nsrc + tn*32 + j];
  }
  __syncthreads();
  #pragma unroll
  for (int l = 0; l < 4; ++l){
    int i = i0 + l*8;
    dst[(size_t)(tn*32 + i)*stride + tk*32 + j] = f2b(lt[j][i]);
  }
}

// ---------------- K-gemm: C[M][N] = A[M][K](bf16) @ Bt[N][K](bf16) + bias; epi ----------------
// epi: 0=none, 1=+bias, 2=gelu(+bias) fp32 out, 3=gelu(+bias) -> bf16 out
__global__ __launch_bounds__(256) void k_gemm(
    const unsigned short* __restrict__ A, const unsigned short* __restrict__ Bt,
    const float* __restrict__ bias, float* __restrict__ C,
    int M, int N, int K, int epi){
  int m0 = blockIdx.x * 64, n0 = blockIdx.y * 64;
  int tid = threadIdx.x;
  int w = tid >> 6, lane = tid & 63;
  int fm = lane & 15, q = lane >> 4;
  __shared__ unsigned short As[64*72];
  __shared__ unsigned short Bs[64*72];
  v4f acc[4] = {};
  int sr = tid >> 2, scb = (tid & 3) * 16;
  const unsigned short* Aga = A + (size_t)(m0 + sr)*K + scb;
  const unsigned short* Bga = Bt + (size_t)(n0 + sr)*K + scb;
  unsigned short* Asd = As + sr*72 + scb;
  unsigned short* Bsd = Bs + sr*72 + scb;
  for (int k0 = 0; k0 < K; k0 += 64){
    uint4 a0 = *(const uint4*)(Aga + k0);
    uint4 a1 = *(const uint4*)(Aga + k0 + 8);
    uint4 b0 = *(const uint4*)(Bga + k0);
    uint4 b1 = *(const uint4*)(Bga + k0 + 8);
    __syncthreads();
    *(uint4*)Asd = a0; *(uint4*)(Asd + 8) = a1;
    *(uint4*)Bsd = b0; *(uint4*)(Bsd + 8) = b1;
    __syncthreads();
    const unsigned short* ap = As + (w*16 + fm)*72 + q*8;
    const unsigned short* bp = Bs + fm*72 + q*8;
    #pragma unroll
    for (int kk = 0; kk < 2; ++kk){
      v8s af = *(const v8s*)(ap + kk*32);
      #pragma unroll
      for (int j = 0; j < 4; ++j){
        v8s bf = *(const v8s*)(bp + j*16*72 + kk*32);
        acc[j] = __builtin_amdgcn_mfma_f32_16x16x32_bf16(af, bf, acc[j], 0, 0, 0);
      }
    }
  }
  #pragma unroll
  for (int j = 0; j < 4; ++j){
    int n = n0 + j*16 + fm;
    float bv = bias ? bias[n] : 0.f;
    if (epi == 3){
      unsigned short* Cp = (unsigned short*)C + (size_t)(m0 + w*16 + q*4)*N + n;
      #pragma unroll
      for (int r = 0; r < 4; ++r)
        Cp[(size_t)r*N] = f2b(gelu(acc[j][r] + bv));
    } else {
      float* Cp = C + (size_t)(m0 + w*16 + q*4)*N + n;
      #pragma unroll
      for (int r = 0; r < 4; ++r){
        float v = acc[j][r] + bv;
        if (epi == 2) v = gelu(v);
        Cp[(size_t)r*N] = v;
      }
    }
  }
}

// ---------------- K-gemmb: batched 64x64-tile GEMM (grid.z = batch) ----------------
// epi 0: relu -> bf16 out ; epi 1: fp32 out (+bias if bias)
__global__ __launch_bounds__(256) void k_gemmb(
    const unsigned short* __restrict__ A, size_t sA,
    const unsigned short* __restrict__ Bt, size_t sB,
    const float* __restrict__ bias, int sbias,
    void* __restrict__ C, size_t sC,
    int M, int N, int K, int epi){
  int e = blockIdx.z;
  const unsigned short* Ae = A + (size_t)e*sA;
  const unsigned short* Be = Bt + (size_t)e*sB;
  const float* biase = bias ? (bias + (size_t)e*sbias) : (const float*)nullptr;
  int m0 = blockIdx.x * 64, n0 = blockIdx.y * 64;
  int tid = threadIdx.x;
  int w = tid >> 6, lane = tid & 63;
  int fm = lane & 15, q = lane >> 4;
  __shared__ unsigned short As[64*72];
  __shared__ unsigned short Bs[64*72];
  v4f acc[4] = {};
  int sr = tid >> 2, scb = (tid & 3) * 16;
  const unsigned short* Aga = Ae + (size_t)(m0 + sr)*K + scb;
  const unsigned short* Bga = Be + (size_t)(n0 + sr)*K + scb;
  unsigned short* Asd = As + sr*72 + scb;
  unsigned short* Bsd = Bs + sr*72 + scb;
  for (int k0 = 0; k0 < K; k0 += 64){
    uint4 a0 = *(const uint4*)(Aga + k0);
    uint4 a1 = *(const uint4*)(Aga + k0 + 8);
    uint4 b0 = *(const uint4*)(Bga + k0);
    uint4 b1 = *(const uint4*)(Bga + k0 + 8);
    __syncthreads();
    *(uint4*)Asd = a0; *(uint4*)(Asd + 8) = a1;
    *(uint4*)Bsd = b0; *(uint4*)(Bsd + 8) = b1;
    __syncthreads();
    const unsigned short* ap = As + (w*16 + fm)*72 + q*8;
    const unsigned short* bp = Bs + fm*72 + q*8;
    #pragma unroll
    for (int kk = 0; kk < 2; ++kk){
      v8s af = *(const v8s*)(ap + kk*32);
      #pragma unroll
      for (int j = 0; j < 4; ++j){
        v8s bf = *(const v8s*)(bp + j*16*72 + kk*32);
        acc[j] = __builtin_amdgcn_mfma_f32_16x16x32_bf16(af, bf, acc[j], 0, 0, 0);
      }
    }
  }
  #pragma unroll
  for (int j = 0; j < 4; ++j){
    int n = n0 + j*16 + fm;
    float bv = biase ? biase[n] : 0.f;
    #pragma unroll
    for (int r = 0; r < 4; ++r){
      float v = acc[j][r] + bv;
      int m = m0 + w*16 + q*4 + r;
      if (epi == 0){
        unsigned short* Cb = (unsigned short*)C + (size_t)e*sC;
        Cb[(size_t)m*N + n] = f2b(fmaxf(v, 0.f));
      } else {
        float* Cf = (float*)C + (size_t)e*sC;
        Cf[(size_t)m*N + n] = v;
      }
    }
  }
}

// ---------------- K-posLN: LN(dpeout + mt) -> posbf [E][64][768] bf16 (pad rows = 0) ----
__global__ void k_posLN(const float* __restrict__ dpeout, const float* __restrict__ mt,
                        const float* __restrict__ lng, const float* __restrict__ lnb,
                        unsigned short* __restrict__ posbf){
  int e = blockIdx.x >> 6, s = blockIdx.x & 63, tid = threadIdx.x;
  size_t ro = (size_t)(e*64 + s)*DD;
  if (s >= SS){
    for (int j = tid; j < DD; j += 256) posbf[ro + j] = 0;
    return;
  }
  __shared__ float red[8];
  float o[3];
  #pragma unroll
  for (int j = 0; j < 3; ++j){
    int d = tid + j*256;
    o[j] = dpeout[ro + d] + mt[(size_t)s*DD + d];
  }
  float mean = block_sum(o[0]+o[1]+o[2], red, 4) * (1.f/DD);
  float dv = 0.f;
  #pragma unroll
  for (int j = 0; j < 3; ++j){ float c = o[j]-mean; dv += c*c; }
  float rstd = rsqrtf(block_sum(dv, red, 4) * (1.f/DD) + LN_EPS);
  #pragma unroll
  for (int j = 0; j < 3; ++j){
    int d = tid + j*256;
    posbf[ro + d] = f2b((o[j]-mean)*rstd*lng[e*DD + d] + lnb[e*DD + d]);
  }
}

// ---------------- K4: router, one token per wave; block-aggregated padded atomics ------
__global__ __launch_bounds__(256) void k_router(
    const float* __restrict__ emb, const int* __restrict__ existing,
    const float* __restrict__ rtrD, const float* __restrict__ ctxFGR,
    const float* __restrict__ rb1, const float* __restrict__ rw2,
    const float* __restrict__ rb2,
    int* __restrict__ cntE, int* __restrict__ listE,
    int* __restrict__ bp0, int* __restrict__ bp1, float* __restrict__ w01,
    unsigned short* __restrict__ secbf){
  int wv = threadIdx.x >> 6, lane = threadIdx.x & 63;
  int tid = threadIdx.x;
  int t = blockIdx.x*4 + wv;
  __shared__ int   easc[8];    // 2 assignments per token, 4 tokens
  __shared__ int   slotA[8];
  int ex = existing[t];
  if (ex){
    const float4* src = (const float4*)(emb + (size_t)t*DD);
    uint2* dst = (uint2*)(secbf + (size_t)t*DD);
    #pragma unroll
    for (int j = 0; j < 3; ++j){
      float4 x = src[lane + j*64];
      uint2 pk;
      pk.x = (unsigned)f2b(x.x) | ((unsigned)f2b(x.y) << 16);
      pk.y = (unsigned)f2b(x.z) | ((unsigned)f2b(x.w) << 16);
      dst[lane + j*64] = pk;
    }
    if (lane == 0){ easc[2*wv] = -1; easc[2*wv+1] = -1; }
  } else {
    int b = t / SS, s = t - b*SS;
    const float* rtrC = ctxFGR + (size_t)b*NCTX + 4096;
    float acc[EE] = {};
    #pragma unroll
    for (int j = 0; j < 4; ++j){
      int idx = lane + j*64;
      float hr = fmaxf(rtrD[s*RR + idx] + rtrC[idx] + rb1[idx], 0.f);
      #pragma unroll
      for (int e = 0; e < EE; ++e) acc[e] += hr * rw2[idx*EE + e];
    }
    #pragma unroll
    for (int e = 0; e < EE; ++e)
      #pragma unroll
      for (int o = 32; o > 0; o >>= 1) acc[e] += __shfl_xor(acc[e], o, 64);
    if (lane == 0){
      float sc[EE];
      float m = -1e30f;
      #pragma unroll
      for (int e = 0; e < EE; ++e){ sc[e] = acc[e] + rb2[e]; m = fmaxf(m, sc[e]); }
      float w[EE]; float Z = 0.f;
      #pragma unroll
      for (int e = 0; e < EE; ++e){ w[e] = expf(sc[e]-m); Z += w[e]; }
      int i0 = 0;
      for (int e = 1; e < EE; ++e) if (w[e] > w[i0]) i0 = e;
      int i1 = -1;
      for (int e = 0; e < EE; ++e) if (e != i0 && (i1 < 0 || w[e] > w[i1])) i1 = e;
      float iz = 1.f/Z;
      easc[2*wv]   = i0; w01[2*t]   = w[i0]*iz;
      easc[2*wv+1] = i1; w01[2*t+1] = w[i1]*iz;
    }
  }
  __syncthreads();
  // one thread per expert: single padded atomic claims the block's slots
  if (tid < EE){
    int e = tid, c = 0;
    #pragma unroll
    for (int j = 0; j < 8; ++j) if (easc[j] == e) ++c;
    if (c){
      int base = atomicAdd(&cntE[e*CPAD], c);
      int sl = base;
      #pragma unroll
      for (int j = 0; j < 8; ++j) if (easc[j] == e) slotA[j] = sl++;
    }
  }
  __syncthreads();
  if (tid < 8){
    int j = tid, e = easc[j];
    if (e >= 0){
      int tt = blockIdx.x*4 + (j >> 1);
      int sl = slotA[j];
      if (sl >= TT) sl = TT - 1;
      listE[e*TT + sl] = tt;
      int bp = (e << 16) | sl;
      if (j & 1) bp1[tt] = bp;
      else       bp0[tt] = bp;
    }
  }
}

// ---------------- K4b: expert offsets + (expert,chunk) work list ----------------
__global__ void k_offsE(const int* __restrict__ cntE, int* __restrict__ offE,
                        int* __restrict__ workE, int* __restrict__ wtotE){
  if (threadIdx.x == 0){
    int acc = 0, wb = 0;
    for (int e = 0; e < EE; ++e){
      offE[e] = acc;
      int n = cntE[e*CPAD]; if (n > TT) n = TT;
      acc += n;
      int nb = (n + 63) >> 6;
      for (int j = 0; j < nb && wb < MAXWORK; ++j) workE[wb++] = (e << 16) | j;
    }
    wtotE[0] = wb;
  }
}

// ---------------- K5a: hf = relu(ctxF+posF+fb1) -> bf16 global; gates ----------------
__global__ __launch_bounds__(256) void k_hfE(
    const float* __restrict__ ctxFGR, const float* __restrict__ posFG,
    const float* __restrict__ fb1,
    const float* __restrict__ gb1, const float* __restrict__ gw2,
    const float* __restrict__ gb2,
    const int* __restrict__ cntE, const int* __restrict__ offE,
    const int* __restrict__ listE,
    const int* __restrict__ workE, const int* __restrict__ wtotE,
    unsigned short* __restrict__ hfg, float* __restrict__ gatesg){
  int wi = blockIdx.x;
  if (wi >= wtotE[0]) return;
  int ent = workE[wi];
  int e = ent >> 16, chunk = ent & 0xffff;
  int n = cntE[e*CPAD]; if (n > TT) n = TT;
  int nt = n - chunk*64; if (nt > 64) nt = 64;
  int base = offE[e] + chunk*64;
  int tid = threadIdx.x, wv = tid >> 6, lane = tid & 63;
  __shared__ int tb[64], ts[64];
  if (tid < 64){
    int ok = tid < nt;
    int t = listE[e*TT + chunk*64 + (ok ? tid : 0)];
    tb[tid] = t/SS; ts[tid] = t - (t/SS)*SS;
  }
  __syncthreads();
  {
    int row = tid >> 2, cb = (tid & 3) * 64;
    if (row < nt){
      int b = tb[row], s = ts[row];
      const float4* cF = (const float4*)(ctxFGR + (size_t)b*NCTX + e*256 + cb);
      const float4* pF = (const float4*)(posFG + ((size_t)(e*64 + s))*512 + cb);
      const float4* bF = (const float4*)(fb1 + (size_t)e*RR + cb);
      uint2* dst = (uint2*)(hfg + (size_t)(base + row)*256 + cb);
      #pragma unroll
      for (int j = 0; j < 16; ++j){
        float4 a = cF[j], p = pF[j], bb = bF[j];
        uint2 pk;
        pk.x = (unsigned)f2b(fmaxf(a.x+p.x+bb.x, 0.f))
             | ((unsigned)f2b(fmaxf(a.y+p.y+bb.y, 0.f)) << 16);
        pk.y = (unsigned)f2b(fmaxf(a.z+p.z+bb.z, 0.f))
             | ((unsigned)f2b(fmaxf(a.w+p.w+bb.w, 0.f)) << 16);
        dst[j] = pk;
      }
    }
  }
  for (int ii = 0; ii < 16; ++ii){
    int row = wv*16 + ii;
    if (row < nt){
      int b = tb[row], s = ts[row];
      float g = 0.f;
      #pragma unroll
      for (int j = 0; j < 4; ++j){
        int idx = lane + j*64;
        float hg = fmaxf(ctxFGR[(size_t)b*NCTX + 2048 + e*256 + idx]
                         + posFG[((size_t)(e*64 + s))*512 + 256 + idx] + gb1[e*RR + idx], 0.f);
        g += hg * gw2[e*RR + idx];
      }
      #pragma unroll
      for (int o = 32; o > 0; o >>= 1) g += __shfl_xor(g, o, 64);
      if (lane == 0) gatesg[base + row] = 1.f/(1.f + expf(-(g + gb2[e])));
    }
  }
}

// ---------------- K5b: expert GEMM tile (chunk, nc) -> cand (pre-LN mix) ----------------
__global__ __launch_bounds__(256) void k_gemmE(
    const unsigned short* __restrict__ hfg, const unsigned short* __restrict__ Wf2t,
    const float* __restrict__ fb2, const float* __restrict__ ctx,
    const float* __restrict__ gatesg,
    const int* __restrict__ cntE, const int* __restrict__ offE,
    const int* __restrict__ listE,
    const int* __restrict__ workE, const int* __restrict__ wtotE,
    float* __restrict__ cand){
  int wi = blockIdx.x;
  if (wi >= wtotE[0]) return;
  int ent = workE[wi];
  int e = ent >> 16, chunk = ent & 0xffff;
  int n = cntE[e*CPAD]; if (n > TT) n = TT;
  int nt = n - chunk*64; if (nt > 64) nt = 64;
  int base = offE[e] + chunk*64;
  int nc = blockIdx.y;
  int tid = threadIdx.x, w = tid >> 6, lane = tid & 63;
  int fm = lane & 15, q = lane >> 4;
  __shared__ unsigned short As[64*72];
  __shared__ unsigned short Bs[64*72];
  __shared__ float gl[64];
  __shared__ int tbl[64];
  if (tid < 64){
    int ok = tid < nt;
    int t = listE[e*TT + chunk*64 + (ok ? tid : 0)];
    tbl[tid] = t/SS;
    gl[tid] = gatesg[base + (ok ? tid : 0)];
  }
  v4f acc[4] = {};
  int sr = tid >> 2, scb = (tid & 3) * 16;
  const unsigned short* Aga = hfg + (size_t)(base + sr)*256 + scb;
  const unsigned short* Bga = Wf2t + (size_t)e*768*256 + (size_t)(nc*64 + sr)*256 + scb;
  unsigned short* Asd = As + sr*72 + scb;
  unsigned short* Bsd = Bs + sr*72 + scb;
  for (int k0 = 0; k0 < 256; k0 += 64){
    uint4 a0 = *(const uint4*)(Aga + k0);
    uint4 a1 = *(const uint4*)(Aga + k0 + 8);
    uint4 b0 = *(const uint4*)(Bga + k0);
    uint4 b1 = *(const uint4*)(Bga + k0 + 8);
    __syncthreads();
    *(uint4*)Asd = a0; *(uint4*)(Asd + 8) = a1;
    *(uint4*)Bsd = b0; *(uint4*)(Bsd + 8) = b1;
    __syncthreads();
    const unsigned short* ap = As + (w*16 + fm)*72 + q*8;
    const unsigned short* bp = Bs + fm*72 + q*8;
    #pragma unroll
    for (int kk = 0; kk < 2; ++kk){
      v8s af = *(const v8s*)(ap + kk*32);
      #pragma unroll
      for (int j = 0; j < 4; ++j){
        v8s bf = *(const v8s*)(bp + j*16*72 + kk*32);
        acc[j] = __builtin_amdgcn_mfma_f32_16x16x32_bf16(af, bf, acc[j], 0, 0, 0);
      }
    }
  }
  #pragma unroll
  for (int j = 0; j < 4; ++j){
    int d = nc*64 + j*16 + fm;
    float fb2v = fb2[(size_t)e*DD + d];
    #pragma unroll
    for (int r = 0; r < 4; ++r){
      int row = w*16 + q*4 + r;
      if (row < nt){
        float g = gl[row];
        float cv = ctx[(size_t)tbl[row]*DD + d];
        cand[(size_t)(base + row)*DD + d] = g*(acc[j][r] + fb2v) + (1.f - g)*cv;
      }
    }
  }
}

// ---------------- K6: per-token gather: LN both cand rows, weighted combine -> secbf --
__global__ void k_gather(const int* __restrict__ existing,
                         const int* __restrict__ bp0, const int* __restrict__ bp1,
                         const float* __restrict__ w01, const int* __restrict__ offE,
                         const float* __restrict__ cand,
                         const float* __restrict__ elng, const float* __restrict__ elnb,
                         unsigned short* __restrict__ secbf){
  int wv = threadIdx.x >> 6, lane = threadIdx.x & 63;
  int t = blockIdx.x*4 + wv;
  if (existing[t]) return;
  int b0v = bp0[t], b1v = bp1[t];
  int e0 = b0v >> 16, e1 = b1v >> 16;
  int g0 = offE[e0] + (b0v & 0xffff);
  int g1 = offE[e1] + (b1v & 0xffff);
  if (g0 >= NACAP) g0 = 0;
  if (g1 >= NACAP) g1 = 0;
  float w0 = w01[2*t], w1 = w01[2*t+1];
  float v0[12], v1[12];
  float s0 = 0.f, q0 = 0.f, s1 = 0.f, q1 = 0.f;
  #pragma unroll
  for (int j = 0; j < 12; ++j){
    int d = lane + j*64;
    v0[j] = cand[(size_t)g0*DD + d];
    v1[j] = cand[(size_t)g1*DD + d];
    s0 += v0[j]; q0 += v0[j]*v0[j];
    s1 += v1[j]; q1 += v1[j]*v1[j];
  }
  #pragma unroll
  for (int o = 32; o > 0; o >>= 1){
    s0 += __shfl_xor(s0, o, 64); q0 += __shfl_xor(q0, o, 64);
    s1 += __shfl_xor(s1, o, 64); q1 += __shfl_xor(q1, o, 64);
  }
  float mean0 = s0*(1.f/DD), mean1 = s1*(1.f/DD);
  float rstd0 = rsqrtf(q0*(1.f/DD) - mean0*mean0 + LN_EPS);
  float rstd1 = rsqrtf(q1*(1.f/DD) - mean1*mean1 + LN_EPS);
  #pragma unroll
  for (int j = 0; j < 12; ++j){
    int d = lane + j*64;
    float o0 = (v0[j]-mean0)*rstd0*elng[e0*DD + d] + elnb[e0*DD + d];
    float o1 = (v1[j]-mean1)*rstd1*elng[e1*DD + d] + elnb[e1*DD + d];
    secbf[(size_t)t*DD + d] = f2b(w0*o0 + w1*o1);
  }
}

// ---------------- K7b: row-LN over R=256 -> bf16 (wave per row) ----------------
__global__ void k_lnR(const float* __restrict__ x2f,
                      const float* __restrict__ lng, const float* __restrict__ lnb,
                      unsigned short* __restrict__ xrbf){
  int wv = threadIdx.x >> 6, lane = threadIdx.x & 63;
  int t = blockIdx.x*4 + wv;
  float v[4];
  float s = 0.f, q = 0.f;
  #pragma unroll
  for (int j = 0; j < 4; ++j){
    v[j] = x2f[(size_t)t*RR + lane + j*64];
    s += v[j]; q += v[j]*v[j];
  }
  #pragma unroll
  for (int o = 32; o > 0; o >>= 1){
    s += __shfl_xor(s, o, 64); q += __shfl_xor(q, o, 64);
  }
  float mean = s*(1.f/RR);
  float rstd = rsqrtf(q*(1.f/RR) - mean*mean + LN_EPS);
  #pragma unroll
  for (int j = 0; j < 4; ++j){
    int d = lane + j*64;
    xrbf[(size_t)t*RR + d] = f2b((v[j]-mean)*rstd*lng[d] + lnb[d]);
  }
}

// ---------------- K9: attention per (b,head); reads qcat [T][768]; writes bf16 ----------------
__global__ void k_attn(const float* __restrict__ qcat, unsigned short* __restrict__ attnbf){
  int bh = blockIdx.x, b = bh / NHH, h = bh % NHH, tid = threadIdx.x;
  __shared__ float qs[SS][HDD], ks[SS][HDD], vs[SS][HDD];
  __shared__ float scr[SS][SS+1];
  for (int idx = tid; idx < SS*HDD; idx += 256){
    int s = idx / HDD, d = idx % HDD;
    size_t g = ((size_t)(b*SS + s))*768 + h*HDD + d;
    qs[s][d] = qcat[g]; ks[s][d] = qcat[g + 256]; vs[s][d] = qcat[g + 512];
  }
  __syncthreads();
  const float scale = 0.17677669529663687f;  // 1/sqrt(32)
  for (int idx = tid; idx < SS*SS; idx += 256){
    int qi = idx / SS, ki = idx % SS;
    float a = 0.f;
    #pragma unroll
    for (int d = 0; d < HDD; ++d) a += qs[qi][d]*ks[ki][d];
    scr[qi][ki] = a*scale;
  }
  __syncthreads();
  if (tid < SS){
    float m = -1e30f;
    for (int ki = 0; ki < SS; ++ki) m = fmaxf(m, scr[tid][ki]);
    float Z = 0.f;
    for (int ki = 0; ki < SS; ++ki){ float e2 = expf(scr[tid][ki]-m); scr[tid][ki] = e2; Z += e2; }
    float iz = 1.f/Z;
    for (int ki = 0; ki < SS; ++ki) scr[tid][ki] *= iz;
  }
  __syncthreads();
  for (int idx = tid; idx < SS*HDD; idx += 256){
    int qi = idx / HDD, d = idx % HDD;
    float a = 0.f;
    for (int ki = 0; ki < SS; ++ki) a += scr[qi][ki]*vs[ki][d];
    attnbf[((size_t)(b*SS + qi))*RR + h*HDD + d] = f2b(a);
  }
}

// ---------------- K10: mean over S + predictor -> logits fp32 ----------------
__global__ void k_final(const float* __restrict__ oproj, const float* __restrict__ pw,
                        const float* __restrict__ pb, float* __restrict__ out){
  int b = blockIdx.x, tid = threadIdx.x;
  __shared__ float om[RR];
  float a = 0.f;
  for (int s = 0; s < SS; ++s) a += oproj[((size_t)(b*SS + s))*RR + tid];
  om[tid] = a * (1.f/SS);
  __syncthreads();
  if (tid < LL){
    float acc = pb[tid];
    for (int h = 0; h < RR; ++h) acc += om[h]*pw[h*LL + tid];
    out[b*LL + tid] = acc;
  }
}

extern "C" void kernel_launch(void* const* d_in, const int* in_sizes, int n_in,
                              void* d_out, int out_size, void* d_ws, size_t ws_size,
                              hipStream_t stream){
  (void)in_sizes; (void)n_in; (void)out_size; (void)ws_size;
  const float* emb      = (const float*)d_in[0];
  const int*   existing = (const int*)d_in[1];
  const float* mt       = (const float*)d_in[2];
  const float* dpe_w0   = (const float*)d_in[3];
  const float* dpe_b0   = (const float*)d_in[4];
  const float* dpe_w1   = (const float*)d_in[5];
  const float* dpe_b1   = (const float*)d_in[6];
  const float* dpe_w2   = (const float*)d_in[7];
  const float* dpe_b2   = (const float*)d_in[8];
  const float* dpe_wo   = (const float*)d_in[9];
  const float* dpe_bo   = (const float*)d_in[10];
  const float* dpe_lng  = (const float*)d_in[11];
  const float* dpe_lnb  = (const float*)d_in[12];
  const float* fus_w1c  = (const float*)d_in[13];
  const float* fus_w1p  = (const float*)d_in[14];
  const float* fus_b1   = (const float*)d_in[15];
  const float* fus_w2   = (const float*)d_in[16];
  const float* fus_b2   = (const float*)d_in[17];
  const float* gate_w1c = (const float*)d_in[18];
  const float* gate_w1p = (const float*)d_in[19];
  const float* gate_b1  = (const float*)d_in[20];
  const float* gate_w2  = (const float*)d_in[21];
  const float* gate_b2  = (const float*)d_in[22];
  const float* exp_lng  = (const float*)d_in[23];
  const float* exp_lnb  = (const float*)d_in[24];
  const float* rtr_w1   = (const float*)d_in[25];
  const float* rtr_b1   = (const float*)d_in[26];
  const float* rtr_w2   = (const float*)d_in[27];
  const float* rtr_b2   = (const float*)d_in[28];
  const float* red_w1   = (const float*)d_in[29];
  const float* red_b1   = (const float*)d_in[30];
  const float* red_w2   = (const float*)d_in[31];
  const float* red_b2   = (const float*)d_in[32];
  const float* red_lng  = (const float*)d_in[33];
  const float* red_lnb  = (const float*)d_in[34];
  const float* qkv_w    = (const float*)d_in[35];
  const float* qkv_b    = (const float*)d_in[36];
  const float* out_w    = (const float*)d_in[37];
  const float* out_b    = (const float*)d_in[38];
  const float* pred_w   = (const float*)d_in[39];
  const float* pred_b   = (const float*)d_in[40];
  float* out = (float*)d_out;

  // workspace layout (float units); aliases noted
  float* wsf = (float*)d_ws;
  size_t off = 0;
  float* ctx    = wsf + off; off += (size_t)BB*DD;
  unsigned short* ctxbf = (unsigned short*)(wsf + off); off += (size_t)BB*DD/2;
  float* ctxFGR = wsf + off; off += (size_t)BB*NCTX;
  int*   cntE   = (int*)(wsf + off); off += EE*CPAD;  // padded counters (256B apart)
  int*   workE  = (int*)(wsf + off); off += MAXWORK;
  int*   wtot   = (int*)(wsf + off); off += 64;     // wtot[0]=total, wtot[8..15]=offE
  int*   offE   = wtot + 8;
  // region A: listE/bp/w01 (dead before k_attn) ; attnbf aliases it afterwards
  float* regA   = wsf + off; off += (size_t)128*TT;
  int*   listE  = (int*)regA;                       // EE*TT ints
  int*   bp0    = (int*)regA + (size_t)EE*TT;       // TT
  int*   bp1    = (int*)regA + (size_t)(EE+1)*TT;   // TT
  float* w01    = regA + (size_t)(EE+2)*TT;         // 2*TT floats
  unsigned short* attnbf = (unsigned short*)regA;   // TT*RR ushort <= region
  // region B: secbf (used through gemm red1) ; oprojf aliases it afterwards
  float* regB   = wsf + off; off += (size_t)TT*DD/2;
  unsigned short* secbf = (unsigned short*)regB;
  float* oprojf = regB;                             // TT*RR floats <= region
  // region C: DPE scratch (early) ; cand ; x1bf/x2f ; qcat (late)
  float* regC   = wsf + off; off += (size_t)NACAP*DD;
  float* dpeout = regC;                                     // 8*64*768 fp32
  unsigned short* posbf = (unsigned short*)(regC + 393216); // 8*64*768 bf16
  unsigned short* h0    = (unsigned short*)(regC + 589824); // 8*64*256 bf16
  unsigned short* h1    = (unsigned short*)(regC + 655360);
  unsigned short* h2    = (unsigned short*)(regC + 720896);
  float* cand   = regC;                             // NACAP*768 floats (after DPE dead)
  unsigned short* x1bf = (unsigned short*)regC;     // TT*HH2 bf16 (after cand dead)
  float* x2f    = regC + 4718592;                   // TT*RR fp32 (disjoint from x1bf)
  float* qcat   = regC;                             // TT*768 floats (after x2f dead)
  // region D: hfg (live k_hfE..k_gemmE) ; xrbf aliases afterwards
  float* regD   = wsf + off; off += (size_t)NACAP*256/2;    // 1572864 floats
  unsigned short* hfg  = (unsigned short*)regD;             // NACAP*256 bf16
  unsigned short* xrbf = (unsigned short*)regD;             // TT*RR bf16 <= region
  unsigned short* Wr1t = (unsigned short*)(wsf + off); off += (size_t)768*384/2;
  unsigned short* Wqt  = (unsigned short*)(wsf + off); off += (size_t)768*256/2;
  unsigned short* Wot  = (unsigned short*)(wsf + off); off += (size_t)256*256/2;
  unsigned short* Wct  = (unsigned short*)(wsf + off); off += (size_t)NCTX*768/2;
  unsigned short* Wf2t = (unsigned short*)(wsf + off); off += (size_t)EE*768*256/2;
  unsigned short* mtbf = (unsigned short*)(wsf + off); off += (size_t)64*768/2;
  unsigned short* W0t  = (unsigned short*)(wsf + off); off += (size_t)EE*256*768/2;
  unsigned short* W1t  = (unsigned short*)(wsf + off); off += (size_t)EE*256*256/2;
  unsigned short* W2t  = (unsigned short*)(wsf + off); off += (size_t)EE*256*256/2;
  unsigned short* Wot2 = (unsigned short*)(wsf + off); off += (size_t)EE*768*256/2;
  unsigned short* Wpgt = (unsigned short*)(wsf + off); off += (size_t)EE*512*768/2;
  unsigned short* Wr1rt= (unsigned short*)(wsf + off); off += (size_t)256*768/2;
  unsigned short* Wr2t = (unsigned short*)(wsf + off); off += (size_t)256*384/2;
  float* posFG  = wsf + off; off += (size_t)EE*64*512;
  float* rtrDp  = wsf + off; off += (size_t)64*256;
  float* gatesg = wsf + off; off += (size_t)NACAP;

  k_context<<<BB, 256, 0, stream>>>(emb, existing, ctx, ctxbf);
  k_mtpad  <<<64, 256, 0, stream>>>(mt, mtbf);
  k_pack   <<<12800, 256, 0, stream>>>(red_w1, qkv_w, out_w, fus_w1c, gate_w1c, fus_w2,
                                       rtr_w1, dpe_w0, dpe_w1, dpe_w2, dpe_wo,
                                       fus_w1p, gate_w1p, red_w2,
                                       Wr1t, Wqt, Wot, Wct, Wf2t,
                                       W0t, W1t, W2t, Wot2, Wpgt, Wr1rt, Wr2t);
  // DPE chain as batched bf16 GEMMs (M=64 padded from 23 rows)
  k_gemmb<<<dim3(1,4,8),  256, 0, stream>>>(mtbf, 0, W0t, (size_t)256*768,
                                            dpe_b0, 256, h0, (size_t)64*256,
                                            64, 256, 768, 0);
  k_gemmb<<<dim3(1,4,8),  256, 0, stream>>>(h0, (size_t)64*256, W1t, (size_t)256*256,
                                            dpe_b1, 256, h1, (size_t)64*256,
                                            64, 256, 256, 0);
  k_gemmb<<<dim3(1,4,8),  256, 0, stream>>>(h1, (size_t)64*256, W2t, (size_t)256*256,
                                            dpe_b2, 256, h2, (size_t)64*256,
                                            64, 256, 256, 0);
  k_gemmb<<<dim3(1,12,8), 256, 0, stream>>>(h2, (size_t)64*256, Wot2, (size_t)768*256,
                                            dpe_bo, 768, dpeout, (size_t)64*768,
                                            64, 768, 256, 1);
  k_posLN<<<512, 256, 0, stream>>>(dpeout, mt, dpe_lng, dpe_lnb, posbf);
  k_gemmb<<<dim3(1,8,8),  256, 0, stream>>>(posbf, (size_t)64*768, Wpgt, (size_t)512*768,
                                            (const float*)nullptr, 0, posFG, (size_t)64*512,
                                            64, 512, 768, 1);
  k_gemmb<<<dim3(1,4,1),  256, 0, stream>>>(mtbf, 0, Wr1rt, 0,
                                            (const float*)nullptr, 0, rtrDp, 0,
                                            64, 256, 768, 1);
  {
    dim3 g(BB/64, NCTX/64);   // (8, 68)
    k_gemm <<<g, 256, 0, stream>>>(ctxbf, Wct, (const float*)nullptr, ctxFGR,
                                   BB, NCTX, DD, 0);
  }
  hipMemsetAsync(cntE, 0, EE*CPAD*sizeof(int), stream);
  k_router <<<TT/4, 256, 0, stream>>>(emb, existing, rtrDp, ctxFGR, rtr_b1, rtr_w2, rtr_b2,
                                      cntE, listE, bp0, bp1, w01, secbf);
  k_offsE  <<<1, 64, 0, stream>>>(cntE, offE, workE, wtot);
  k_hfE    <<<384, 256, 0, stream>>>(ctxFGR, posFG, fus_b1,
                                     gate_b1, gate_w2, gate_b2,
                                     cntE, offE, listE, workE, wtot, hfg, gatesg);
  k_gemmE  <<<dim3(384,12), 256, 0, stream>>>(hfg, Wf2t, fus_b2, ctx, gatesg,
                                              cntE, offE, listE, workE, wtot, cand);
  k_gather <<<TT/4, 256, 0, stream>>>(existing, bp0, bp1, w01, offE, cand,
                                      exp_lng, exp_lnb, secbf);
  {
    dim3 g(TT/64, HH2/64);    // (184, 6)
    k_gemm <<<g, 256, 0, stream>>>(secbf, Wr1t, red_b1, (float*)x1bf, TT, HH2, DD, 3);
  }
  {
    dim3 g(TT/64, RR/64);     // (184, 4)
    k_gemm <<<g, 256, 0, stream>>>(x1bf, Wr2t, red_b2, x2f, TT, RR, HH2, 2);
  }
  k_lnR    <<<TT/4, 256, 0, stream>>>(x2f, red_lng, red_lnb, xrbf);
  {
    dim3 g(TT/64, 768/64);    // (184, 12)
    k_gemm <<<g, 256, 0, stream>>>(xrbf, Wqt, qkv_b, qcat, TT, 768, RR, 1);
  }
  k_attn   <<<BB*NHH, 256, 0, stream>>>(qcat, attnbf);
  {
    dim3 g(TT/64, RR/64);     // (184, 4)
    k_gemm <<<g, 256, 0, stream>>>(attnbf, Wot, out_b, oprojf, TT, RR, RR, 1);
  }
  k_final  <<<BB, 256, 0, stream>>>(oprojf, pred_w, pred_b, out);
}